// Round 5
// baseline (197.616 us; speedup 1.0000x reference)
//
#include <hip/hip_runtime.h>
#include <math.h>

// SSIM loss, fp32, B=16 C=3 H=W=512, 11x11 Gaussian (sigma=1.5), zero pad.
// R5: spill-free streaming horizontal pass + packed-f32 row-pair math.
//  - hb[pair][plane][65] h2 in LDS: plane stride 65 dwords -> ds_read2/write2
//    mergeable; all accesses bank = j + const (<=2-way, free).
//  - horizontal: scatter form, float2 (row0,row1) packed ops -> v_pk_fma_f32,
//    v_cvt_pkrtz_f16_f32 pack + single b32 write per (plane,col).
//  - vertical: unchanged dot2 structure (2 taps/instr), f16-weight cv fixup.

#define IMG_W 512
#define IMG_H 512
#define PLANES 48
#define TX 64
#define TY 32
#define RAD 5
#define KW 11
#define NPAIR 21               // (TY + 2*RAD) / 2
#define SJ 65                  // col stride (odd -> conflict-free)
#define NT 256
#define GDX (IMG_W / TX)       // 8
#define GDY (IMG_H / TY)       // 16
#define NBLK (GDX * GDY * PLANES)  // 6144

typedef _Float16 h2 __attribute__((ext_vector_type(2)));
typedef float    f2 __attribute__((ext_vector_type(2)));

#if __has_builtin(__builtin_amdgcn_fdot2)
__device__ __forceinline__ float DOT2(h2 a, h2 b, float c) {
    return __builtin_amdgcn_fdot2(a, b, c, false);
}
#else
__device__ __forceinline__ float DOT2(h2 a, h2 b, float c) {
    return c + (float)a.x * (float)b.x + (float)a.y * (float)b.y;
}
#endif

__device__ __forceinline__ h2 pkrtz(float a, float b) {
    auto t = __builtin_amdgcn_cvt_pkrtz(a, b);
    h2 r;
    __builtin_memcpy(&r, &t, sizeof(r));
    return r;
}

// One horizontal item: row-pair pp, 4-col group g4. Streaming scatter form:
// each loaded input column is consumed immediately into <=4 packed accums.
template<bool INTERIOR>
__device__ __forceinline__ void hpass_item(
    int pp, int g4, int ty0, int bx0,
    const float* __restrict__ xp, const float* __restrict__ yp,
    h2 (* __restrict__ hb)[5][SJ], const float* __restrict__ w)
{
    const int j0  = bx0 + g4 * 4;
    const int gy0 = ty0 + 2 * pp;
    const int gy1 = gy0 + 1;
    const bool ok0 = INTERIOR || ((unsigned)gy0 < (unsigned)IMG_H);
    const bool ok1 = INTERIOR || ((unsigned)gy1 < (unsigned)IMG_H);
    const float* r0x = xp + (size_t)gy0 * IMG_W;
    const float* r1x = xp + (size_t)gy1 * IMG_W;
    const float* r0y = yp + (size_t)gy0 * IMG_W;
    const float* r1y = yp + (size_t)gy1 * IMG_W;

    f2 aX[4], aY[4], aXX[4], aYY[4], aXY[4];
    #pragma unroll
    for (int cc = 0; cc < 4; ++cc) {
        aX[cc] = (f2)0.f; aY[cc] = (f2)0.f;
        aXX[cc] = (f2)0.f; aYY[cc] = (f2)0.f; aXY[cc] = (f2)0.f;
    }

    const float4 z4 = make_float4(0.f, 0.f, 0.f, 0.f);
    #pragma unroll
    for (int v = 0; v < 5; ++v) {
        const int gx = j0 - 8 + 4 * v;   // multiple of 4: chunk never straddles
        const bool colok = INTERIOR || ((unsigned)gx < (unsigned)IMG_W);
        const float4 x0 = (colok && ok0) ? *(const float4*)(r0x + gx) : z4;
        const float4 x1 = (colok && ok1) ? *(const float4*)(r1x + gx) : z4;
        const float4 y0 = (colok && ok0) ? *(const float4*)(r0y + gx) : z4;
        const float4 y1 = (colok && ok1) ? *(const float4*)(r1y + gx) : z4;

        #pragma unroll
        for (int i = 0; i < 4; ++i) {
            const int t = 4 * v + i;            // window col 0..19
            if (t < 3 || t > 16) continue;      // only cols j0-5..j0+8 used
            const float e0x = ((const float*)&x0)[i];
            const float e1x = ((const float*)&x1)[i];
            const float e0y = ((const float*)&y0)[i];
            const float e1y = ((const float*)&y1)[i];
            f2 px; px.x = e0x; px.y = e1x;
            f2 py; py.x = e0y; py.y = e1y;
            const f2 pxx = px * px;
            const f2 pyy = py * py;
            const f2 pxy = px * py;
            const int clo = (t - 13) > 0 ? (t - 13) : 0;
            const int chi = (t - 3) < 3 ? (t - 3) : 3;
            #pragma unroll
            for (int cc = clo; cc <= chi; ++cc) {
                const float wk = w[t - 3 - cc];
                f2 wv; wv.x = wk; wv.y = wk;
                aX[cc]  += wv * px;
                aY[cc]  += wv * py;
                aXX[cc] += wv * pxx;
                aYY[cc] += wv * pyy;
                aXY[cc] += wv * pxy;
            }
        }
    }

    #pragma unroll
    for (int cc = 0; cc < 4; ++cc) {
        const int c = g4 * 4 + cc;
        hb[pp][0][c] = pkrtz(aX[cc].x,  aX[cc].y);
        hb[pp][1][c] = pkrtz(aY[cc].x,  aY[cc].y);
        hb[pp][2][c] = pkrtz(aXX[cc].x, aXX[cc].y);
        hb[pp][3][c] = pkrtz(aYY[cc].x, aYY[cc].y);
        hb[pp][4][c] = pkrtz(aXY[cc].x, aXY[cc].y);
    }
}

__global__ __launch_bounds__(NT, 4) void ssim_tile_kernel(
    const float* __restrict__ x, const float* __restrict__ y,
    float* __restrict__ partials)
{
    __shared__ h2 hb[NPAIR][5][SJ];     // 27300 B
    __shared__ float wave_sums[NT / 64];

    // Normalized f32 weights (horizontal, exact); f16 copies for vertical.
    float w[KW];
    {
        float s = 0.f;
        #pragma unroll
        for (int k = 0; k < KW; ++k) {
            const float d = (float)(k - RAD);
            w[k] = expf(-d * d * (1.f / (2.f * 1.5f * 1.5f)));
            s += w[k];
        }
        const float inv = 1.f / s;
        #pragma unroll
        for (int k = 0; k < KW; ++k) w[k] *= inv;
    }
    _Float16 wh[KW];
    float cv;
    {
        float s2 = 0.f;
        #pragma unroll
        for (int k = 0; k < KW; ++k) { wh[k] = (_Float16)w[k]; s2 += (float)wh[k]; }
        cv = 1.f / s2;   // f16 weight-sum correction
    }
    // Pair-weight tables: w2[parity of output row][pair offset q].
    h2 w2[2][6];
    #pragma unroll
    for (int q = 0; q < 5; ++q) { w2[0][q].x = wh[2*q];   w2[0][q].y = wh[2*q+1]; }
    w2[0][5].x = wh[10]; w2[0][5].y = (_Float16)0.f;
    w2[1][0].x = (_Float16)0.f; w2[1][0].y = wh[0];
    #pragma unroll
    for (int q = 1; q < 6; ++q) { w2[1][q].x = wh[2*q-1]; w2[1][q].y = wh[2*q]; }

    const int tid = threadIdx.x;
    const int plane = blockIdx.z;
    const float* __restrict__ xp = x + (size_t)plane * IMG_H * IMG_W;
    const float* __restrict__ yp = y + (size_t)plane * IMG_H * IMG_W;
    const int bx0 = blockIdx.x * TX;
    const int ty0 = blockIdx.y * TY - RAD;

    const bool interior =
        (bx0 >= 8) && (bx0 + TX - 4 + 12 <= IMG_W) &&
        (ty0 >= 0) && (ty0 + 2 * NPAIR <= IMG_H);

    // ---- Horizontal pass: 336 items = 21 row-pairs x 16 col-quads ----
    if (interior) {
        hpass_item<true>(tid >> 4, tid & 15, ty0, bx0, xp, yp, hb, w);
        if (tid < NPAIR * 16 - NT)
            hpass_item<true>(16 + (tid >> 4), tid & 15, ty0, bx0, xp, yp, hb, w);
    } else {
        hpass_item<false>(tid >> 4, tid & 15, ty0, bx0, xp, yp, hb, w);
        if (tid < NPAIR * 16 - NT)
            hpass_item<false>(16 + (tid >> 4), tid & 15, ty0, bx0, xp, yp, hb, w);
    }
    __syncthreads();

    // ---- Vertical pass: 1 col x 8 output rows per thread, dot2 taps ----
    const int j  = tid & 63;
    const int P0 = (tid >> 6) * 4;      // first row-pair of this chunk

    float acc[5][8];
    #pragma unroll
    for (int p = 0; p < 5; ++p)
        #pragma unroll
        for (int u = 0; u < 8; ++u) acc[p][u] = 0.f;

    #pragma unroll
    for (int pp = 0; pp < 9; ++pp) {
        h2 v[5];
        #pragma unroll
        for (int p = 0; p < 5; ++p)
            v[p] = hb[P0 + pp][p][j];
        const int ulo = (2 * pp - 10) > 0 ? (2 * pp - 10) : 0;
        const int uhi = (2 * pp + 1) < 7 ? (2 * pp + 1) : 7;
        #pragma unroll
        for (int u = ulo; u <= uhi; ++u) {
            const h2 wv = w2[u & 1][pp - (u >> 1)];
            #pragma unroll
            for (int p = 0; p < 5; ++p)
                acc[p][u] = DOT2(v[p], wv, acc[p][u]);
        }
    }

    // ---- SSIM map + local sum ----
    float local = 0.f;
    #pragma unroll
    for (int u = 0; u < 8; ++u) {
        const float mx = acc[0][u] * cv, my = acc[1][u] * cv;
        const float xx = acc[2][u] * cv, yy = acc[3][u] * cv, xy = acc[4][u] * cv;
        const float mx2 = mx * mx, my2 = my * my, mxy = mx * my;
        const float sx2 = xx - mx2, sy2 = yy - my2, sxy = xy - mxy;
        const float c1 = 1e-4f, c2 = 9e-4f;
        const float num = (2.f * mxy + c1) * (2.f * sxy + c2);
        const float den = (mx2 + my2 + c1) * (sx2 + sy2 + c2) + 1e-8f;
        local += num * __builtin_amdgcn_rcpf(den);
    }

    // ---- Block reduction -> one partial per block ----
    #pragma unroll
    for (int off = 32; off > 0; off >>= 1)
        local += __shfl_down(local, off, 64);
    const int lane = tid & 63, wv = tid >> 6;
    if (lane == 0) wave_sums[wv] = local;
    __syncthreads();
    if (tid == 0) {
        const float s = wave_sums[0] + wave_sums[1] + wave_sums[2] + wave_sums[3];
        const int bid = blockIdx.x + GDX * (blockIdx.y + GDY * blockIdx.z);
        partials[bid] = s;
    }
}

__global__ __launch_bounds__(NT) void ssim_finalize_kernel(
    const float* __restrict__ partials, float* __restrict__ out)
{
    const int tid = threadIdx.x;
    double s = 0.0;
    #pragma unroll 4
    for (int i = tid; i < NBLK; i += NT) s += (double)partials[i];
    #pragma unroll
    for (int off = 32; off > 0; off >>= 1)
        s += __shfl_down(s, off, 64);
    __shared__ double ws_[NT / 64];
    const int lane = tid & 63, wv = tid >> 6;
    if (lane == 0) ws_[wv] = s;
    __syncthreads();
    if (tid == 0) {
        const double t = ws_[0] + ws_[1] + ws_[2] + ws_[3];
        const double n = (double)PLANES * IMG_H * IMG_W;
        out[0] = (float)(1.0 - t / n);
    }
}

extern "C" void kernel_launch(void* const* d_in, const int* in_sizes, int n_in,
                              void* d_out, int out_size, void* d_ws, size_t ws_size,
                              hipStream_t stream)
{
    const float* x = (const float*)d_in[0];
    const float* y = (const float*)d_in[1];
    float* out = (float*)d_out;
    float* partials = (float*)d_ws;   // NBLK floats, fully overwritten each call

    dim3 grid(GDX, GDY, PLANES);
    ssim_tile_kernel<<<grid, NT, 0, stream>>>(x, y, partials);
    ssim_finalize_kernel<<<1, NT, 0, stream>>>(partials, out);
}

// Round 6
// 151.609 us; speedup vs baseline: 1.3035x; 1.3035x over previous
//
#include <hip/hip_runtime.h>
#include <math.h>

// SSIM loss, fp32, B=16 C=3 H=W=512, 11x11 Gaussian (sigma=1.5), zero pad.
// R6: gather-form single-row horizontal items (R3 register shape, no spill)
//     + f16 row-pair LDS layout hb[pair][5][65] (R5, conflict-light)
//     + dot2 vertical pass (R4/R5) with RNE f16 packing.

#define IMG_W 512
#define IMG_H 512
#define PLANES 48
#define TX 64
#define TY 32
#define RAD 5
#define KW 11
#define NPAIR 21               // (TY + 2*RAD) / 2
#define SJ 65                  // col stride in dwords (odd -> conflict-free)
#define NT 256
#define GDX (IMG_W / TX)       // 8
#define GDY (IMG_H / TY)       // 16
#define NBLK (GDX * GDY * PLANES)  // 6144

typedef _Float16 h2 __attribute__((ext_vector_type(2)));

#if __has_builtin(__builtin_amdgcn_fdot2)
__device__ __forceinline__ float DOT2(h2 a, h2 b, float c) {
    return __builtin_amdgcn_fdot2(a, b, c, false);
}
#else
__device__ __forceinline__ float DOT2(h2 a, h2 b, float c) {
    return c + (float)a.x * (float)b.x + (float)a.y * (float)b.y;
}
#endif

// One horizontal item: image row r (hb row), 8-col group g. Gather form:
// all 12 float4 loads issued up front, then products, then conv, then 40
// RNE f16 half-writes into hb[pair][plane][col] (parity rr picks the half).
template<bool INTERIOR>
__device__ __forceinline__ void hpass_item(
    int r, int g, int ty0, int bx0,
    const float* __restrict__ xp, const float* __restrict__ yp,
    _Float16* __restrict__ hbh,          // [NPAIR][5][SJ][2] halves
    const float* __restrict__ w)
{
    const int gy = ty0 + r;
    const int j0 = bx0 + g * 8;

    float av[24], bv[24];
    const bool rowok = INTERIOR || ((unsigned)gy < (unsigned)IMG_H);
    if (rowok) {
        const float* rowx = xp + (size_t)gy * IMG_W;
        const float* rowy = yp + (size_t)gy * IMG_W;
        #pragma unroll
        for (int v = 0; v < 6; ++v) {
            const int gx = j0 - 8 + 4 * v;   // multiple of 4: no straddle
            float4 xa, ya;
            if (INTERIOR || ((unsigned)gx < (unsigned)IMG_W)) {
                xa = *(const float4*)(rowx + gx);
                ya = *(const float4*)(rowy + gx);
            } else {
                xa = make_float4(0.f, 0.f, 0.f, 0.f);
                ya = make_float4(0.f, 0.f, 0.f, 0.f);
            }
            av[4*v+0] = xa.x; av[4*v+1] = xa.y; av[4*v+2] = xa.z; av[4*v+3] = xa.w;
            bv[4*v+0] = ya.x; bv[4*v+1] = ya.y; bv[4*v+2] = ya.z; bv[4*v+3] = ya.w;
        }
    } else {
        #pragma unroll
        for (int i = 0; i < 24; ++i) { av[i] = 0.f; bv[i] = 0.f; }
    }

    // Products once per used input col (j0-5 .. j0+12 -> av[3..20]).
    float AA[18], BB[18], AB[18];
    #pragma unroll
    for (int i = 0; i < 18; ++i) {
        const float A = av[i + 3], B = bv[i + 3];
        AA[i] = A * A; BB[i] = B * B; AB[i] = A * B;
    }

    const int pp = r >> 1, rr = r & 1;
    #pragma unroll
    for (int u = 0; u < 8; ++u) {
        float sxv = 0.f, syv = 0.f, sxx = 0.f, syy = 0.f, sxy = 0.f;
        #pragma unroll
        for (int k = 0; k < KW; ++k) {
            const float wk = w[k];
            sxv += wk * av[u + 3 + k];
            syv += wk * bv[u + 3 + k];
            sxx += wk * AA[u + k];
            syy += wk * BB[u + k];
            sxy += wk * AB[u + k];
        }
        const int c = g * 8 + u;
        const int base = ((pp * 5 + 0) * SJ + c) * 2 + rr;
        const int pstr = SJ * 2;
        hbh[base + 0 * pstr] = (_Float16)sxv;   // RNE casts
        hbh[base + 1 * pstr] = (_Float16)syv;
        hbh[base + 2 * pstr] = (_Float16)sxx;
        hbh[base + 3 * pstr] = (_Float16)syy;
        hbh[base + 4 * pstr] = (_Float16)sxy;
    }
}

__global__ __launch_bounds__(NT, 4) void ssim_tile_kernel(
    const float* __restrict__ x, const float* __restrict__ y,
    float* __restrict__ partials)
{
    __shared__ h2 hb[NPAIR][5][SJ];     // 27300 B
    __shared__ float wave_sums[NT / 64];

    // Normalized f32 weights (horizontal, exact); f16 copies for vertical.
    float w[KW];
    {
        float s = 0.f;
        #pragma unroll
        for (int k = 0; k < KW; ++k) {
            const float d = (float)(k - RAD);
            w[k] = expf(-d * d * (1.f / (2.f * 1.5f * 1.5f)));
            s += w[k];
        }
        const float inv = 1.f / s;
        #pragma unroll
        for (int k = 0; k < KW; ++k) w[k] *= inv;
    }
    _Float16 wh[KW];
    float cv;
    {
        float s2 = 0.f;
        #pragma unroll
        for (int k = 0; k < KW; ++k) { wh[k] = (_Float16)w[k]; s2 += (float)wh[k]; }
        cv = 1.f / s2;   // f16 weight-sum correction
    }
    // Pair-weight tables: w2[parity of output row][pair offset q].
    h2 w2[2][6];
    #pragma unroll
    for (int q = 0; q < 5; ++q) { w2[0][q].x = wh[2*q];   w2[0][q].y = wh[2*q+1]; }
    w2[0][5].x = wh[10]; w2[0][5].y = (_Float16)0.f;
    w2[1][0].x = (_Float16)0.f; w2[1][0].y = wh[0];
    #pragma unroll
    for (int q = 1; q < 6; ++q) { w2[1][q].x = wh[2*q-1]; w2[1][q].y = wh[2*q]; }

    const int tid = threadIdx.x;
    const int plane = blockIdx.z;
    const float* __restrict__ xp = x + (size_t)plane * IMG_H * IMG_W;
    const float* __restrict__ yp = y + (size_t)plane * IMG_H * IMG_W;
    const int bx0 = blockIdx.x * TX;
    const int ty0 = blockIdx.y * TY - RAD;

    const bool interior =
        (bx0 >= 8) && (bx0 + TX + 8 <= IMG_W) &&
        (ty0 >= 0) && (ty0 + 2 * NPAIR <= IMG_H);

    _Float16* hbh = (_Float16*)hb;

    // ---- Horizontal pass: 336 items = 42 rows x 8 col-groups ----
    if (interior) {
        hpass_item<true>(tid >> 3, tid & 7, ty0, bx0, xp, yp, hbh, w);
        if (tid < 42 * 8 - NT)
            hpass_item<true>(32 + (tid >> 3), tid & 7, ty0, bx0, xp, yp, hbh, w);
    } else {
        hpass_item<false>(tid >> 3, tid & 7, ty0, bx0, xp, yp, hbh, w);
        if (tid < 42 * 8 - NT)
            hpass_item<false>(32 + (tid >> 3), tid & 7, ty0, bx0, xp, yp, hbh, w);
    }
    __syncthreads();

    // ---- Vertical pass: 1 col x 8 output rows per thread, dot2 taps ----
    const int j  = tid & 63;
    const int P0 = (tid >> 6) * 4;      // first row-pair of this chunk

    float acc[5][8];
    #pragma unroll
    for (int p = 0; p < 5; ++p)
        #pragma unroll
        for (int u = 0; u < 8; ++u) acc[p][u] = 0.f;

    #pragma unroll
    for (int pp = 0; pp < 9; ++pp) {
        h2 v[5];
        #pragma unroll
        for (int p = 0; p < 5; ++p)
            v[p] = hb[P0 + pp][p][j];
        const int ulo = (2 * pp - 10) > 0 ? (2 * pp - 10) : 0;
        const int uhi = (2 * pp + 1) < 7 ? (2 * pp + 1) : 7;
        #pragma unroll
        for (int u = ulo; u <= uhi; ++u) {
            const h2 wv = w2[u & 1][pp - (u >> 1)];
            #pragma unroll
            for (int p = 0; p < 5; ++p)
                acc[p][u] = DOT2(v[p], wv, acc[p][u]);
        }
    }

    // ---- SSIM map + local sum ----
    float local = 0.f;
    #pragma unroll
    for (int u = 0; u < 8; ++u) {
        const float mx = acc[0][u] * cv, my = acc[1][u] * cv;
        const float xx = acc[2][u] * cv, yy = acc[3][u] * cv, xy = acc[4][u] * cv;
        const float mx2 = mx * mx, my2 = my * my, mxy = mx * my;
        const float sx2 = xx - mx2, sy2 = yy - my2, sxy = xy - mxy;
        const float c1 = 1e-4f, c2 = 9e-4f;
        const float num = (2.f * mxy + c1) * (2.f * sxy + c2);
        const float den = (mx2 + my2 + c1) * (sx2 + sy2 + c2) + 1e-8f;
        local += num * __builtin_amdgcn_rcpf(den);
    }

    // ---- Block reduction -> one partial per block ----
    #pragma unroll
    for (int off = 32; off > 0; off >>= 1)
        local += __shfl_down(local, off, 64);
    const int lane = tid & 63, wv = tid >> 6;
    if (lane == 0) wave_sums[wv] = local;
    __syncthreads();
    if (tid == 0) {
        const float s = wave_sums[0] + wave_sums[1] + wave_sums[2] + wave_sums[3];
        const int bid = blockIdx.x + GDX * (blockIdx.y + GDY * blockIdx.z);
        partials[bid] = s;
    }
}

__global__ __launch_bounds__(NT) void ssim_finalize_kernel(
    const float* __restrict__ partials, float* __restrict__ out)
{
    const int tid = threadIdx.x;
    double s = 0.0;
    #pragma unroll 4
    for (int i = tid; i < NBLK; i += NT) s += (double)partials[i];
    #pragma unroll
    for (int off = 32; off > 0; off >>= 1)
        s += __shfl_down(s, off, 64);
    __shared__ double ws_[NT / 64];
    const int lane = tid & 63, wv = tid >> 6;
    if (lane == 0) ws_[wv] = s;
    __syncthreads();
    if (tid == 0) {
        const double t = ws_[0] + ws_[1] + ws_[2] + ws_[3];
        const double n = (double)PLANES * IMG_H * IMG_W;
        out[0] = (float)(1.0 - t / n);
    }
}

extern "C" void kernel_launch(void* const* d_in, const int* in_sizes, int n_in,
                              void* d_out, int out_size, void* d_ws, size_t ws_size,
                              hipStream_t stream)
{
    const float* x = (const float*)d_in[0];
    const float* y = (const float*)d_in[1];
    float* out = (float*)d_out;
    float* partials = (float*)d_ws;   // NBLK floats, fully overwritten each call

    dim3 grid(GDX, GDY, PLANES);
    ssim_tile_kernel<<<grid, NT, 0, stream>>>(x, y, partials);
    ssim_finalize_kernel<<<1, NT, 0, stream>>>(partials, out);
}